// Round 7
// baseline (433.479 us; speedup 1.0000x reference)
//
#include <hip/hip_runtime.h>
#include <hip/hip_bf16.h>
#include <math.h>

#define BB 256
#define TT 512
#define DIN 64
#define ZZ 32
#define HH 64

typedef __attribute__((ext_vector_type(4))) float f32x4;
typedef __attribute__((ext_vector_type(8))) __bf16 bf16x8;

__device__ __forceinline__ f32x4 mfma16(bf16x8 a, bf16x8 b, f32x4 c) {
  return __builtin_amdgcn_mfma_f32_16x16x32_bf16(a, b, c, 0, 0, 0);
}

// elu = min(v, e^v - 1): identical for v<=0, exact for v>0, inf-safe.
__device__ __forceinline__ float elu1(float v) {
  return fminf(v, __expf(v) - 1.f);
}
__device__ __forceinline__ f32x4 elu4(f32x4 v) {
  f32x4 r;
  r.x = elu1(v.x); r.y = elu1(v.y); r.z = elu1(v.z); r.w = elu1(v.w);
  return r;
}

// pack two f32x4 (tile0 regs, tile1 regs) into a bf16x8 MFMA operand.
// Slot (q,e) holds k = 16*(e>>2) + 4q + (e&3) == neuron held by D tiles.
__device__ __forceinline__ bf16x8 pack2(f32x4 a, f32x4 b) {
  bf16x8 r;
  r[0] = (__bf16)a.x; r[1] = (__bf16)a.y; r[2] = (__bf16)a.z; r[3] = (__bf16)a.w;
  r[4] = (__bf16)b.x; r[5] = (__bf16)b.y; r[6] = (__bf16)b.z; r[7] = (__bf16)b.w;
  return r;
}

// hi/lo split pack: hi = RNE bf16, lo = bf16(v - float(hi)).
__device__ __forceinline__ void packhl(f32x4 a, f32x4 b, bf16x8& hi, bf16x8& lo) {
  hi = pack2(a, b);
  f32x4 ra, rb;
  ra.x = (float)hi[0]; ra.y = (float)hi[1]; ra.z = (float)hi[2]; ra.w = (float)hi[3];
  rb.x = (float)hi[4]; rb.y = (float)hi[5]; rb.z = (float)hi[6]; rb.w = (float)hi[7];
  lo = pack2(a - ra, b - rb);
}

__device__ __forceinline__ bf16x8 ldw(const float* rowp, int o1, int o2) {
  f32x4 a = *reinterpret_cast<const f32x4*>(rowp + o1);
  f32x4 b = *reinterpret_cast<const f32x4*>(rowp + o2);
  return pack2(a, b);
}
__device__ __forceinline__ void ldw2(const float* rowp, int o1, int o2,
                                     bf16x8& hi, bf16x8& lo) {
  f32x4 a = *reinterpret_cast<const f32x4*>(rowp + o1);
  f32x4 b = *reinterpret_cast<const f32x4*>(rowp + o2);
  packhl(a, b, hi, lo);
}

// tanh via exp + raw v_rcp (rel err ~1ulp fp32 -- far below bf16 noise).
__device__ __forceinline__ float tanh1(float x) {
  float t = __expf(2.f * x);
  return fmaf(-2.f, __builtin_amdgcn_rcpf(t + 1.f), 1.f);
}
__device__ __forceinline__ f32x4 tanh4(f32x4 v) {
  f32x4 r;
  r.x = tanh1(v.x); r.y = tanh1(v.y); r.z = tanh1(v.z); r.w = tanh1(v.w);
  return r;
}

// async global->LDS, 16B per lane. LDS dest is wave-uniform base; HW writes
// lane i at base + i*16. Global src is per-lane.
__device__ __forceinline__ void gload16(const float* g, f32x4* l) {
  __builtin_amdgcn_global_load_lds(
      (const __attribute__((address_space(1))) unsigned int*)g,
      (__attribute__((address_space(3))) unsigned int*)l,
      16, 0, 0);
}

// ---------------------------------------------------------------------------
// prep_kernel: P0[b,t] = (bi0+bh0) + x[b,t] @ Wi0^T for all 131072 rows.
// (unchanged from R6, verified passing)
// ---------------------------------------------------------------------------
__global__ __launch_bounds__(256, 2) void prep_kernel(
    const float* __restrict__ x,
    const float* __restrict__ Wi0,
    const float* __restrict__ bi0, const float* __restrict__ bh0,
    float* __restrict__ p0)
{
  const int lane = threadIdx.x & 63;
  const int wv = threadIdx.x >> 6;
  const int q = lane >> 4, c = lane & 15;

  bf16x8 Wh[2][2], Wl[2][2];   // [kt][mt]
  #pragma unroll
  for (int kt = 0; kt < 2; ++kt)
    #pragma unroll
    for (int mt = 0; mt < 2; ++mt)
      ldw2(Wi0 + (16 * mt + c) * 64, 32 * kt + 4 * q, 32 * kt + 16 + 4 * q,
           Wh[kt][mt], Wl[kt][mt]);
  f32x4 B0[2];
  #pragma unroll
  for (int mt = 0; mt < 2; ++mt)
    B0[mt] = *reinterpret_cast<const f32x4*>(bi0 + 16 * mt + 4 * q) +
             *reinterpret_cast<const f32x4*>(bh0 + 16 * mt + 4 * q);

  const unsigned row = blockIdx.x * 64u + (unsigned)wv * 16u + (unsigned)c;
  const float* xp = x + (size_t)row * DIN;
  f32x4 x0 = *reinterpret_cast<const f32x4*>(xp + 4 * q);
  f32x4 x1 = *reinterpret_cast<const f32x4*>(xp + 16 + 4 * q);
  f32x4 x2 = *reinterpret_cast<const f32x4*>(xp + 32 + 4 * q);
  f32x4 x3 = *reinterpret_cast<const f32x4*>(xp + 48 + 4 * q);
  bf16x8 xf0 = pack2(x0, x1), xf1 = pack2(x2, x3);

  float* pout = p0 + (size_t)row * ZZ;
  #pragma unroll
  for (int mt = 0; mt < 2; ++mt) {
    f32x4 a = mfma16(Wh[0][mt], xf0, B0[mt]);
    a = mfma16(Wl[0][mt], xf0, a);
    a = mfma16(Wh[1][mt], xf1, a);
    a = mfma16(Wl[1][mt], xf1, a);
    *reinterpret_cast<f32x4*>(pout + 16 * mt + 4 * q) = a;
  }
}

// ---------------------------------------------------------------------------
// rnn_kernel: fused 64-wide recurrence (math identical to R6), with P0
// staged through LDS in double-buffered 16-step groups via global_load_lds.
// Exactly one s_waitcnt vmcnt(0) per 16 steps -> memory wait is structurally
// bounded (~30 cy/step) instead of compiler-dependent.
// ---------------------------------------------------------------------------
__global__ __launch_bounds__(64, 1) void rnn_kernel(
    const float* __restrict__ p0buf,
    const float* __restrict__ Wh0,
    const float* __restrict__ Wi1, const float* __restrict__ Wh1,
    const float* __restrict__ bi1, const float* __restrict__ bh1,
    const float* __restrict__ h0g,
    float* __restrict__ rnn, float* __restrict__ out)
{
  __shared__ __align__(16) f32x4 lds4[4096];   // 64 KB: [buf][slot16][half][lane]
  const int lane = threadIdx.x & 63;
  const int q = lane >> 4, c = lane & 15;
  const int b0 = blockIdx.x * 16;
  const f32x4 Z4 = {0.f, 0.f, 0.f, 0.f};

  // ---- weight A-fragments (hi/lo) ----
  bf16x8 W0h[2], W0l[2];            // Wh0, K=32
  #pragma unroll
  for (int mt = 0; mt < 2; ++mt)
    ldw2(Wh0 + (16 * mt + c) * 32, 4 * q, 16 + 4 * q, W0h[mt], W0l[mt]);
  bf16x8 W1h[2][2], W1l[2][2];      // [kt][mt]; kt0 = Wi1, kt1 = Wh1
  #pragma unroll
  for (int mt = 0; mt < 2; ++mt) {
    ldw2(Wi1 + (16 * mt + c) * 32, 4 * q, 16 + 4 * q, W1h[0][mt], W1l[0][mt]);
    ldw2(Wh1 + (16 * mt + c) * 32, 4 * q, 16 + 4 * q, W1h[1][mt], W1l[1][mt]);
  }
  f32x4 B1[2];
  #pragma unroll
  for (int mt = 0; mt < 2; ++mt)
    B1[mt] = *reinterpret_cast<const f32x4*>(bi1 + 16 * mt + 4 * q) +
             *reinterpret_cast<const f32x4*>(bh1 + 16 * mt + 4 * q);

  // ---- initial state z = [h0_init; h1_init] ----
  bf16x8 zh0, zl0, zh1, zl1;
  {
    f32x4 u0 = *reinterpret_cast<const f32x4*>(h0g + 4 * q);
    f32x4 u1 = *reinterpret_cast<const f32x4*>(h0g + 16 + 4 * q);
    packhl(u0, u1, zh0, zl0);
    u0 = *reinterpret_cast<const f32x4*>(h0g + 32 + 4 * q);
    u1 = *reinterpret_cast<const f32x4*>(h0g + 48 + 4 * q);
    packhl(u0, u1, zh1, zl1);
  }

  const float* pp = p0buf + (size_t)(b0 + c) * TT * ZZ;
  float* pr = rnn + (size_t)(b0 + c) * TT * ZZ;
  float* po = out + (size_t)(b0 + c) * TT * ZZ;

  auto sgi = [&](int buf, int s, int hh) {
    return ((buf * 16 + s) * 2 + hh) * 64;
  };
  auto stage_group = [&](int tbase, int buf) {
    #pragma unroll 4
    for (int s = 0; s < 16; ++s) {
      int t = tbase - s;
      if (t < 0) t = 0;
      const float* src = pp + (size_t)t * ZZ + 4 * q;
      gload16(src,      &lds4[sgi(buf, s, 0)]);
      gload16(src + 16, &lds4[sgi(buf, s, 1)]);
    }
  };

  // ---- peel t=511: compute h0(511) only (direct load, one-time) ----
  {
    const float* pt = pp + (size_t)511 * ZZ;
    f32x4 Pm0 = *reinterpret_cast<const f32x4*>(pt + 4 * q);
    f32x4 Pm1 = *reinterpret_cast<const f32x4*>(pt + 16 + 4 * q);
    f32x4 dm0 = mfma16(W0h[0], zh0, Pm0);
    f32x4 dm1 = mfma16(W0h[1], zh0, Pm1);
    f32x4 dl0 = mfma16(W0l[0], zh0, mfma16(W0h[0], zl0, Z4));
    f32x4 dl1 = mfma16(W0l[1], zh0, mfma16(W0h[1], zl0, Z4));
    f32x4 d0 = tanh4(dm0 + dl0), d1 = tanh4(dm1 + dl1);
    packhl(d0, d1, zh0, zl0);
  }

  // ---- prologue: stage first group, wait once, read slot 0 ----
  stage_group(510, 0);
  asm volatile("s_waitcnt vmcnt(0)" ::: "memory");
  f32x4 Pc0 = lds4[sgi(0, 0, 0) + lane];
  f32x4 Pc1 = lds4[sgi(0, 0, 1) + lane];

  #pragma unroll 1
  for (int g = 0; g < 32; ++g) {
    const int tbase = 510 - 16 * g;
    const int buf = g & 1;
    if (g + 1 < 32) stage_group(tbase - 16, buf ^ 1);

    #pragma unroll 4
    for (int s = 0; s < 16; ++s) {
      const int t = tbase - s;     // -1 only at the very last slot
      // prefetch next slot's P (slot 15 reads slot 0 garbage, replaced below)
      f32x4 Pn0 = lds4[sgi(buf, (s + 1) & 15, 0) + lane];
      f32x4 Pn1 = lds4[sgi(buf, (s + 1) & 15, 1) + lane];
      if (t >= 0) {
        // h0-outputs (K=32): 3 MFMA x 2 tiles
        f32x4 dm0 = mfma16(W0h[0], zh0, Pc0);
        f32x4 dm1 = mfma16(W0h[1], zh0, Pc1);
        f32x4 dl0 = mfma16(W0l[0], zh0, mfma16(W0h[0], zl0, Z4));
        f32x4 dl1 = mfma16(W0l[1], zh0, mfma16(W0h[1], zl0, Z4));
        // h1-outputs (K=64): 6 MFMA x 2 tiles
        f32x4 ea0 = mfma16(W1h[1][0], zh1, mfma16(W1h[0][0], zh0, B1[0]));
        f32x4 ea1 = mfma16(W1h[1][1], zh1, mfma16(W1h[0][1], zh0, B1[1]));
        f32x4 eb0 = mfma16(W1h[1][0], zl1, mfma16(W1h[0][0], zl0, Z4));
        f32x4 eb1 = mfma16(W1h[1][1], zl1, mfma16(W1h[0][1], zl0, Z4));
        f32x4 ec0 = mfma16(W1l[1][0], zh1, mfma16(W1l[0][0], zh0, Z4));
        f32x4 ec1 = mfma16(W1l[1][1], zh1, mfma16(W1l[0][1], zh0, Z4));
        f32x4 d0 = tanh4(dm0 + dl0), d1 = tanh4(dm1 + dl1);
        f32x4 e0 = tanh4(ea0 + (eb0 + ec0)), e1 = tanh4(ea1 + (eb1 + ec1));
        // store h1(t+1)
        float* prt = pr + (size_t)(t + 1) * ZZ;
        *reinterpret_cast<f32x4*>(prt + 4 * q) = e0;
        *reinterpret_cast<f32x4*>(prt + 16 + 4 * q) = e1;
        if (t == 510) {   // h1(511) also goes to out row 511
          float* pot = po + (size_t)511 * ZZ;
          *reinterpret_cast<f32x4*>(pot + 4 * q) = e0;
          *reinterpret_cast<f32x4*>(pot + 16 + 4 * q) = e1;
        }
        packhl(d0, d1, zh0, zl0);
        packhl(e0, e1, zh1, zl1);
      }
      Pc0 = Pn0; Pc1 = Pn1;
    }

    // single per-group wait: next buffer's staging is now complete
    asm volatile("s_waitcnt vmcnt(0)" ::: "memory");
    Pc0 = lds4[sgi(buf ^ 1, 0, 0) + lane];
    Pc1 = lds4[sgi(buf ^ 1, 0, 1) + lane];
  }
}

// ---------------------------------------------------------------------------
// ODE kernel: unchanged from R6 (verified passing).
// ---------------------------------------------------------------------------
__global__ __launch_bounds__(256, 2) void ode_kernel(
    const float* __restrict__ rnn,
    const float* __restrict__ w1, const float* __restrict__ b1,
    const float* __restrict__ w2, const float* __restrict__ b2,
    const float* __restrict__ w3, const float* __restrict__ b3,
    float* __restrict__ out)
{
  const int lane = threadIdx.x & 63;
  const int wv = threadIdx.x >> 6;
  const int q = lane >> 4, c = lane & 15;

  bf16x8 W1[4], W2[2][4], W3[2][2];
  f32x4 BZ1[4], BZ2[4], BZ3[2];
  #pragma unroll
  for (int mt = 0; mt < 4; ++mt) {
    W1[mt] = ldw(w1 + (16 * mt + c) * 32, 4 * q, 16 + 4 * q);
    BZ1[mt] = *reinterpret_cast<const f32x4*>(b1 + 16 * mt + 4 * q);
    BZ2[mt] = *reinterpret_cast<const f32x4*>(b2 + 16 * mt + 4 * q);
  }
  #pragma unroll
  for (int kt = 0; kt < 2; ++kt)
    #pragma unroll
    for (int mt = 0; mt < 4; ++mt)
      W2[kt][mt] = ldw(w2 + (16 * mt + c) * 64, 32 * kt + 4 * q, 32 * kt + 16 + 4 * q);
  #pragma unroll
  for (int kt = 0; kt < 2; ++kt)
    #pragma unroll
    for (int mt = 0; mt < 2; ++mt)
      W3[kt][mt] = ldw(w3 + (16 * mt + c) * 64, 32 * kt + 4 * q, 32 * kt + 16 + 4 * q);
  #pragma unroll
  for (int mt = 0; mt < 2; ++mt)
    BZ3[mt] = *reinterpret_cast<const f32x4*>(b3 + 16 * mt + 4 * q);

  const unsigned row = 16u * (blockIdx.x * 4u + (unsigned)wv) + (unsigned)c;
  const unsigned bb = row / 511u, tp = row - bb * 511u;
  const float* srcp = rnn + ((size_t)bb * TT + tp + 1) * ZZ;
  f32x4 y0 = *reinterpret_cast<const f32x4*>(srcp + 4 * q);
  f32x4 y1 = *reinterpret_cast<const f32x4*>(srcp + 16 + 4 * q);

  f32x4 k0, k1, ks0, ks1;

  auto feval = [&](bf16x8 xf, f32x4& o0, f32x4& o1) {
    f32x4 a[4];
    #pragma unroll
    for (int mt = 0; mt < 4; ++mt) a[mt] = mfma16(W1[mt], xf, BZ1[mt]);
    #pragma unroll
    for (int mt = 0; mt < 4; ++mt) a[mt] = elu4(a[mt]);
    bf16x8 h10 = pack2(a[0], a[1]), h11 = pack2(a[2], a[3]);
    f32x4 g[4];
    #pragma unroll
    for (int mt = 0; mt < 4; ++mt)
      g[mt] = mfma16(W2[1][mt], h11, mfma16(W2[0][mt], h10, BZ2[mt]));
    #pragma unroll
    for (int mt = 0; mt < 4; ++mt) g[mt] = elu4(g[mt]);
    bf16x8 h20 = pack2(g[0], g[1]), h21 = pack2(g[2], g[3]);
    o0 = mfma16(W3[1][0], h21, mfma16(W3[0][0], h20, BZ3[0]));
    o1 = mfma16(W3[1][1], h21, mfma16(W3[0][1], h20, BZ3[1]));
  };

  const float hs = 0.01f;
  #pragma unroll 1
  for (int it = 0; it < 9; ++it) {
    feval(pack2(y0, y1), k0, k1);
    ks0 = k0; ks1 = k1;
    feval(pack2(y0 + (0.5f * hs) * k0, y1 + (0.5f * hs) * k1), k0, k1);
    ks0 += 2.f * k0; ks1 += 2.f * k1;
    feval(pack2(y0 + (0.5f * hs) * k0, y1 + (0.5f * hs) * k1), k0, k1);
    ks0 += 2.f * k0; ks1 += 2.f * k1;
    feval(pack2(y0 + hs * k0, y1 + hs * k1), k0, k1);
    y0 += (hs / 6.f) * (ks0 + k0);
    y1 += (hs / 6.f) * (ks1 + k1);
  }

  float* dstp = out + ((size_t)bb * TT + tp) * ZZ;
  *reinterpret_cast<f32x4*>(dstp + 4 * q) = y0;
  *reinterpret_cast<f32x4*>(dstp + 16 + 4 * q) = y1;
}

// ---------------------------------------------------------------------------
extern "C" void kernel_launch(void* const* d_in, const int* in_sizes, int n_in,
                              void* d_out, int out_size, void* d_ws, size_t ws_size,
                              hipStream_t stream) {
  const float* x   = (const float*)d_in[0];
  const float* Wi0 = (const float*)d_in[1];
  const float* Wh0 = (const float*)d_in[2];
  const float* bi0 = (const float*)d_in[3];
  const float* bh0 = (const float*)d_in[4];
  const float* Wi1 = (const float*)d_in[5];
  const float* Wh1 = (const float*)d_in[6];
  const float* bi1 = (const float*)d_in[7];
  const float* bh1 = (const float*)d_in[8];
  const float* h0  = (const float*)d_in[9];
  const float* w1  = (const float*)d_in[10];
  const float* b1  = (const float*)d_in[11];
  const float* w2  = (const float*)d_in[12];
  const float* b2  = (const float*)d_in[13];
  const float* w3  = (const float*)d_in[14];
  const float* b3  = (const float*)d_in[15];
  float* out = (float*)d_out;
  float* rnn = (float*)d_ws;      // B*T*Z fp32 = 16.7 MB scratch
  float* p0  = (float*)d_out;     // d_out doubles as P0 scratch; every byte
                                  // is overwritten later (ode rows 0..510,
                                  // rnn row 511) before validation.

  prep_kernel<<<2048, 256, 0, stream>>>(x, Wi0, bi0, bh0, p0);
  rnn_kernel<<<16, 64, 0, stream>>>(p0, Wh0, Wi1, Wh1, bi1, bh1, h0, rnn, out);
  ode_kernel<<<2044, 256, 0, stream>>>(rnn, w1, b1, w2, b2, w3, b3, out);
}